// Round 2
// baseline (2155.505 us; speedup 1.0000x reference)
//
#include <hip/hip_runtime.h>
#include <hip/hip_bf16.h>

// B=2, S=2048, HID=4096, NH=32, D=128, G=8, GS=4, RK=256, FGD=256, FH=8192
typedef __hip_bfloat16 bf16;
typedef __bf16 bf16x8 __attribute__((ext_vector_type(8)));
typedef float f32x4 __attribute__((ext_vector_type(4)));

#define MFMA16(a, b, c) __builtin_amdgcn_mfma_f32_16x16x32_bf16(a, b, c, 0, 0, 0)

__device__ __forceinline__ void llds16(const bf16* g, bf16* lds) {
  __builtin_amdgcn_global_load_lds(
      (const __attribute__((address_space(1))) unsigned int*)g,
      (__attribute__((address_space(3))) unsigned int*)lds, 16, 0, 0);
}

__device__ __forceinline__ void storeC(float* p, float v) { *p = v; }
__device__ __forceinline__ void storeC(bf16* p, float v) { *p = __float2bfloat16(v); }

// ---------------- fp32 -> bf16 convert (vectorized) ----------------
__global__ __launch_bounds__(256) void cvt_f2b(const float* __restrict__ in,
                                               bf16* __restrict__ out, int n4) {
  int i = blockIdx.x * 256 + threadIdx.x;
  if (i >= n4) return;
  float4 v = ((const float4*)in)[i];
  union { bf16 h[4]; short4 s; } u;
  u.h[0] = __float2bfloat16(v.x);
  u.h[1] = __float2bfloat16(v.y);
  u.h[2] = __float2bfloat16(v.z);
  u.h[3] = __float2bfloat16(v.w);
  ((short4*)out)[i] = u.s;
}

// ---------------- generic bf16 GEMM: C = A(MxK,lda) . B(NxK,ldb)^T ----------------
template <typename OUT_T>
__global__ __launch_bounds__(256) void gemm_bt(
    const bf16* __restrict__ A, const bf16* __restrict__ B, OUT_T* __restrict__ C,
    int M, int N, int K, int lda, int ldb, int ldc,
    long batchA, long batchB, long batchC) {
  __shared__ alignas(16) bf16 As[128 * 32];
  __shared__ alignas(16) bf16 Bs[128 * 32];
  const int t = threadIdx.x;
  const int w = t >> 6, l = t & 63;
  const int lane_r = l & 15, quad = l >> 4;
  const int wm = (w >> 1) * 64, wn = (w & 1) * 64;
  const long m0 = (long)blockIdx.y * 128, n0 = (long)blockIdx.x * 128;
  A += (long)blockIdx.z * batchA;
  B += (long)blockIdx.z * batchB;
  C += (long)blockIdx.z * batchC;
  const int r0a = t >> 2;
  const int cba = (t & 3) * 8;
  f32x4 acc[4][4] = {};
  for (int k0 = 0; k0 < K; k0 += 32) {
    llds16(A + (m0 + r0a) * lda + k0 + cba, &As[t * 8]);
    llds16(A + (m0 + r0a + 64) * lda + k0 + cba, &As[(t + 256) * 8]);
    llds16(B + (n0 + r0a) * ldb + k0 + cba, &Bs[t * 8]);
    llds16(B + (n0 + r0a + 64) * ldb + k0 + cba, &Bs[(t + 256) * 8]);
    __syncthreads();
    bf16x8 af[4], bfr[4];
#pragma unroll
    for (int mt = 0; mt < 4; ++mt)
      af[mt] = *(const bf16x8*)&As[(wm + mt * 16 + lane_r) * 32 + quad * 8];
#pragma unroll
    for (int nt = 0; nt < 4; ++nt)
      bfr[nt] = *(const bf16x8*)&Bs[(wn + nt * 16 + lane_r) * 32 + quad * 8];
#pragma unroll
    for (int mt = 0; mt < 4; ++mt)
#pragma unroll
      for (int nt = 0; nt < 4; ++nt)
        acc[mt][nt] = MFMA16(af[mt], bfr[nt], acc[mt][nt]);
    __syncthreads();
  }
#pragma unroll
  for (int mt = 0; mt < 4; ++mt)
#pragma unroll
    for (int nt = 0; nt < 4; ++nt) {
      long row = m0 + wm + mt * 16 + quad * 4;
      long col = n0 + wn + nt * 16 + lane_r;
#pragma unroll
      for (int r = 0; r < 4; ++r) storeC(&C[(row + r) * ldc + col], acc[mt][nt][r]);
    }
}

// ---------------- RoPE in place on (B,S,NH,128) bf16 ----------------
__global__ __launch_bounds__(256) void rope_kernel(bf16* __restrict__ X,
                                                   const int* __restrict__ pos_ids) {
  int idx = blockIdx.x * 256 + threadIdx.x;
  int d = idx & 63;
  int h = (idx >> 6) & 31;
  int bs = idx >> 11;
  float pos = (float)pos_ids[bs];
  float inv = exp2f(-(float)d * (13.287712379549449f / 64.0f));
  float fr = pos * inv, sn, cs;
  sincosf(fr, &sn, &cs);
  long base = (long)bs * 4096 + h * 128 + d;
  float x1 = __bfloat162float(X[base]);
  float x2 = __bfloat162float(X[base + 64]);
  X[base] = __float2bfloat16(x1 * cs - x2 * sn);
  X[base + 64] = __float2bfloat16(x2 * cs + x1 * sn);
}

// ---------------- transpose v_lat (b, s, 2048) -> vt (b, 2048, s) ----------------
__global__ __launch_bounds__(256) void transpose_kernel(const bf16* __restrict__ v,
                                                        bf16* __restrict__ vt) {
  __shared__ bf16 tile[32][33];
  int b = blockIdx.z;
  int c0 = blockIdx.x * 32;
  int r0 = blockIdx.y * 32;
  int tx = threadIdx.x & 31, ty = threadIdx.x >> 5;
#pragma unroll
  for (int p = 0; p < 4; ++p) {
    int r = ty + p * 8;
    tile[r][tx] = v[((long)b * 2048 + r0 + r) * 2048 + c0 + tx];
  }
  __syncthreads();
#pragma unroll
  for (int p = 0; p < 4; ++p) {
    int c = ty + p * 8;
    vt[((long)b * 2048 + c0 + c) * 2048 + r0 + tx] = tile[tx][c];
  }
}

// ---------------- flash attention v2: 128-row Q tiles, 8 waves, XOR-swizzled LDS ---
// grid (S/128 reversed, NH, B), 512 threads; wave w owns q rows [q0+16w, q0+16w+16)
// LDS swizzle: 16B chunk c of row r stored at chunk slot (c ^ (r & (CH-1))), CH=chunks/row.
__global__ __launch_bounds__(512, 4) void attn_kernel(const bf16* __restrict__ Q,
                                                      const bf16* __restrict__ Kg,
                                                      const bf16* __restrict__ Vt,
                                                      bf16* __restrict__ fused) {
  __shared__ alignas(16) bf16 Ks[64 * 128];   // (kv, d) CH=16
  __shared__ alignas(16) bf16 Vs[256 * 64];   // (d, kv) CH=8
  __shared__ alignas(16) bf16 Ps[8][16 * 64]; // per-wave P (row, kv) CH=8
  const int t = threadIdx.x, w = t >> 6, l = t & 63;
  const int lane_r = l & 15, quad = l >> 4;
  const int qt = (int)gridDim.x - 1 - (int)blockIdx.x;  // long blocks dispatch first
  const int q0 = qt * 128, h = blockIdx.y, b = blockIdx.z;
  const int g = h >> 2, j = h & 3;
  const int qr0 = q0 + w * 16;
  const float scale = 0.08838834764831845f;  // 1/sqrt(128)

  // Q fragments (A-operand: m=lane&15, k=quad*8+j)
  const bf16* qbase = Q + ((long)(b * 2048 + qr0 + lane_r)) * 4096 + h * 128 + quad * 8;
  bf16x8 qf[4];
#pragma unroll
  for (int kd = 0; kd < 4; ++kd) qf[kd] = *(const bf16x8*)(qbase + kd * 32);

  f32x4 acc[16] = {};
  float m_i[4], l_i[4];
#pragma unroll
  for (int r = 0; r < 4; ++r) { m_i[r] = -1e30f; l_i[r] = 0.f; }

  const bf16* Kbase = Kg + (long)b * 2048 * 4096 + h * 128;
  const bf16* Vbase = Vt + ((long)(b * 8 + g)) * 256 * 2048;
  const int nk = (q0 >> 6) + 2;  // causal kv tiles covering q0..q0+127

  for (int kt = 0; kt < nk; ++kt) {
    const int k0 = kt * 64;
    // stage K tile 64x128: 1024 chunks, swizzled source
#pragma unroll
    for (int p = 0; p < 2; ++p) {
      int s = t + p * 512;
      int r = s >> 4, c = (s & 15) ^ (r & 15);
      llds16(Kbase + (long)(k0 + r) * 4096 + c * 8, &Ks[s * 8]);
    }
    // stage V^T tile 256x64: 2048 chunks, swizzled source
#pragma unroll
    for (int p = 0; p < 4; ++p) {
      int s = t + p * 512;
      int r = s >> 3, c = (s & 7) ^ (r & 7);
      llds16(Vbase + (long)r * 2048 + k0 + c * 8, &Vs[s * 8]);
    }
    __syncthreads();

    // QK^T: 16 rows x 64 cols per wave
    float sc[4][4];
#pragma unroll
    for (int ks = 0; ks < 4; ++ks) {
      f32x4 s = {};
#pragma unroll
      for (int kd = 0; kd < 4; ++kd) {
        int csw = (kd * 4 + quad) ^ lane_r;  // row&15 == lane_r
        bf16x8 kf = *(const bf16x8*)&Ks[(ks * 16 + lane_r) * 128 + csw * 8];
        s = MFMA16(qf[kd], kf, s);
      }
      const int kv = k0 + ks * 16 + lane_r;
#pragma unroll
      for (int r = 0; r < 4; ++r) {
        int qrow = qr0 + quad * 4 + r;
        sc[ks][r] = (kv <= qrow) ? s[r] * scale : -1e30f;
      }
    }
    // online softmax per row
#pragma unroll
    for (int r = 0; r < 4; ++r) {
      float mx = fmaxf(fmaxf(sc[0][r], sc[1][r]), fmaxf(sc[2][r], sc[3][r]));
#pragma unroll
      for (int o = 1; o < 16; o <<= 1) mx = fmaxf(mx, __shfl_xor(mx, o));
      float mnew = fmaxf(m_i[r], mx);
      float alpha = __expf(m_i[r] - mnew);
      float rs = 0.f;
#pragma unroll
      for (int ks = 0; ks < 4; ++ks) {
        float p = __expf(sc[ks][r] - mnew);
        sc[ks][r] = p;
        rs += p;
      }
#pragma unroll
      for (int o = 1; o < 16; o <<= 1) rs += __shfl_xor(rs, o);
      l_i[r] = l_i[r] * alpha + rs;
      m_i[r] = mnew;
#pragma unroll
      for (int nt = 0; nt < 16; ++nt) acc[nt][r] *= alpha;
    }
    // P: C-layout -> LDS (swizzled), wave-private so no barrier needed before PV
#pragma unroll
    for (int ks = 0; ks < 4; ++ks)
#pragma unroll
      for (int r = 0; r < 4; ++r) {
        int row = quad * 4 + r, col = ks * 16 + lane_r;
        int csw = ((col >> 3) ^ (row & 7));
        Ps[w][row * 64 + csw * 8 + (col & 7)] = __float2bfloat16(sc[ks][r]);
      }
    // PV: acc[nt] += P(16x64) . V^T(d-subtile nt)(16x64)^T
#pragma unroll
    for (int kq = 0; kq < 2; ++kq) {
      int pcs = (kq * 4 + quad) ^ (lane_r & 7);
      bf16x8 pf = *(const bf16x8*)&Ps[w][lane_r * 64 + pcs * 8];
#pragma unroll
      for (int nt = 0; nt < 16; ++nt) {
        int vcs = (kq * 4 + quad) ^ (lane_r & 7);  // row&7 == lane_r&7
        bf16x8 vf = *(const bf16x8*)&Vs[(nt * 16 + lane_r) * 64 + vcs * 8];
        acc[nt] = MFMA16(pf, vf, acc[nt]);
      }
    }
    __syncthreads();
  }
  // epilogue: normalize + scatter to PALU-scrambled fused layout
#pragma unroll
  for (int r = 0; r < 4; ++r) {
    float inv = 1.0f / l_i[r];
    int qrow = qr0 + quad * 4 + r;
    int sOut = j * 512 + (qrow >> 2);
    int fi = qrow & 3;
    bf16* obase = fused + ((long)(b * 2048 + sOut)) * 8192 + fi * 2048 + g * 256 + lane_r;
#pragma unroll
    for (int nt = 0; nt < 16; ++nt) obase[nt * 16] = __float2bfloat16(acc[nt][r] * inv);
  }
}

// ---------------- launch ----------------
extern "C" void kernel_launch(void* const* d_in, const int* in_sizes, int n_in,
                              void* d_out, int out_size, void* d_ws, size_t ws_size,
                              hipStream_t stream) {
  const float* hidden = (const float*)d_in[0];
  const int* pos_ids = (const int*)d_in[2];
  const float* Wq = (const float*)d_in[3];
  const float* WVT = (const float*)d_in[4];
  const float* U = (const float*)d_in[5];
  const float* Wv = (const float*)d_in[6];
  const float* Wo = (const float*)d_in[7];
  float* out = (float*)d_out;

  bf16* ws = (bf16*)d_ws;
  bf16* WB = ws;                    // 33554432 elems (reused for Wq/WVT/Wv/Wo)
  bf16* UB = WB + 33554432;         // 1048576
  bf16* hidB = UB + 1048576;        // 16777216
  bf16* Qb = hidB + 16777216;       // 16777216
  bf16* Kb = Qb + 16777216;         // 16777216
  bf16* klatB = Kb + 16777216;      // 8388608
  bf16* vlatB = klatB + 8388608;    // 8388608
  bf16* vtB = vlatB + 8388608;      // 8388608
  bf16* fusedB = vtB + 8388608;     // 33554432

  cvt_f2b<<<16384, 256, 0, stream>>>(hidden, hidB, 16777216 / 4);
  cvt_f2b<<<16384, 256, 0, stream>>>(Wq, WB, 16777216 / 4);
  gemm_bt<bf16><<<dim3(32, 32, 1), 256, 0, stream>>>(hidB, WB, Qb, 4096, 4096, 4096,
                                                     4096, 4096, 4096, 0, 0, 0);
  cvt_f2b<<<8192, 256, 0, stream>>>(WVT, WB, 8388608 / 4);
  gemm_bt<bf16><<<dim3(16, 32, 1), 256, 0, stream>>>(hidB, WB, klatB, 4096, 2048, 4096,
                                                     4096, 4096, 2048, 0, 0, 0);
  cvt_f2b<<<8192, 256, 0, stream>>>(Wv, WB, 8388608 / 4);
  gemm_bt<bf16><<<dim3(16, 32, 1), 256, 0, stream>>>(hidB, WB, vlatB, 4096, 2048, 4096,
                                                     4096, 4096, 2048, 0, 0, 0);
  cvt_f2b<<<1024, 256, 0, stream>>>(U, UB, 1048576 / 4);
  gemm_bt<bf16><<<dim3(4, 32, 8), 256, 0, stream>>>(klatB, UB, Kb, 4096, 512, 256,
                                                    2048, 2048, 4096, 256, 256, 512);
  rope_kernel<<<32768, 256, 0, stream>>>(Qb, pos_ids);
  rope_kernel<<<32768, 256, 0, stream>>>(Kb, pos_ids);
  transpose_kernel<<<dim3(64, 64, 2), 256, 0, stream>>>(vlatB, vtB);
  cvt_f2b<<<32768, 256, 0, stream>>>(Wo, WB, 33554432 / 4);
  attn_kernel<<<dim3(16, 32, 2), 512, 0, stream>>>(Qb, Kb, vtB, fusedB);
  gemm_bt<float><<<dim3(32, 32, 1), 256, 0, stream>>>(fusedB, WB, out, 4096, 4096, 8192,
                                                      8192, 8192, 4096, 0, 0, 0);
}

// Round 3
// 2060.501 us; speedup vs baseline: 1.0461x; 1.0461x over previous
//
#include <hip/hip_runtime.h>
#include <hip/hip_bf16.h>

// B=2, S=2048, HID=4096, NH=32, D=128, G=8, GS=4, RK=256, FGD=256, FH=8192
typedef __hip_bfloat16 bf16;
typedef __bf16 bf16x8 __attribute__((ext_vector_type(8)));
typedef float f32x4 __attribute__((ext_vector_type(4)));

#define MFMA16(a, b, c) __builtin_amdgcn_mfma_f32_16x16x32_bf16(a, b, c, 0, 0, 0)

__device__ __forceinline__ void llds16(const bf16* g, bf16* lds) {
  __builtin_amdgcn_global_load_lds(
      (const __attribute__((address_space(1))) unsigned int*)g,
      (__attribute__((address_space(3))) unsigned int*)lds, 16, 0, 0);
}

__device__ __forceinline__ void storeC(float* p, float v) { *p = v; }
__device__ __forceinline__ void storeC(bf16* p, float v) { *p = __float2bfloat16(v); }

// ---------------- fp32 -> bf16 convert (vectorized) ----------------
__global__ __launch_bounds__(256) void cvt_f2b(const float* __restrict__ in,
                                               bf16* __restrict__ out, int n4) {
  int i = blockIdx.x * 256 + threadIdx.x;
  if (i >= n4) return;
  float4 v = ((const float4*)in)[i];
  union { bf16 h[4]; short4 s; } u;
  u.h[0] = __float2bfloat16(v.x);
  u.h[1] = __float2bfloat16(v.y);
  u.h[2] = __float2bfloat16(v.z);
  u.h[3] = __float2bfloat16(v.w);
  ((short4*)out)[i] = u.s;
}

// ---------------- generic bf16 GEMM: C = A(MxK,lda) . B(NxK,ldb)^T ----------------
template <typename OUT_T>
__global__ __launch_bounds__(256) void gemm_bt(
    const bf16* __restrict__ A, const bf16* __restrict__ B, OUT_T* __restrict__ C,
    int M, int N, int K, int lda, int ldb, int ldc,
    long batchA, long batchB, long batchC) {
  __shared__ alignas(16) bf16 As[128 * 32];
  __shared__ alignas(16) bf16 Bs[128 * 32];
  const int t = threadIdx.x;
  const int w = t >> 6, l = t & 63;
  const int lane_r = l & 15, quad = l >> 4;
  const int wm = (w >> 1) * 64, wn = (w & 1) * 64;
  const long m0 = (long)blockIdx.y * 128, n0 = (long)blockIdx.x * 128;
  A += (long)blockIdx.z * batchA;
  B += (long)blockIdx.z * batchB;
  C += (long)blockIdx.z * batchC;
  const int r0a = t >> 2;
  const int cba = (t & 3) * 8;
  f32x4 acc[4][4] = {};
  for (int k0 = 0; k0 < K; k0 += 32) {
    llds16(A + (m0 + r0a) * lda + k0 + cba, &As[t * 8]);
    llds16(A + (m0 + r0a + 64) * lda + k0 + cba, &As[(t + 256) * 8]);
    llds16(B + (n0 + r0a) * ldb + k0 + cba, &Bs[t * 8]);
    llds16(B + (n0 + r0a + 64) * ldb + k0 + cba, &Bs[(t + 256) * 8]);
    __syncthreads();
    bf16x8 af[4], bfr[4];
#pragma unroll
    for (int mt = 0; mt < 4; ++mt)
      af[mt] = *(const bf16x8*)&As[(wm + mt * 16 + lane_r) * 32 + quad * 8];
#pragma unroll
    for (int nt = 0; nt < 4; ++nt)
      bfr[nt] = *(const bf16x8*)&Bs[(wn + nt * 16 + lane_r) * 32 + quad * 8];
#pragma unroll
    for (int mt = 0; mt < 4; ++mt)
#pragma unroll
      for (int nt = 0; nt < 4; ++nt)
        acc[mt][nt] = MFMA16(af[mt], bfr[nt], acc[mt][nt]);
    __syncthreads();
  }
#pragma unroll
  for (int mt = 0; mt < 4; ++mt)
#pragma unroll
    for (int nt = 0; nt < 4; ++nt) {
      long row = m0 + wm + mt * 16 + quad * 4;
      long col = n0 + wn + nt * 16 + lane_r;
#pragma unroll
      for (int r = 0; r < 4; ++r) storeC(&C[(row + r) * ldc + col], acc[mt][nt][r]);
    }
}

// ------- RoPE + layout permute: (B,S,NH,128) -> (B,NH,S,128), out-of-place -------
__global__ __launch_bounds__(256) void rope_perm(const bf16* __restrict__ in,
                                                 bf16* __restrict__ out,
                                                 const int* __restrict__ pos_ids) {
  int idx = blockIdx.x * 256 + threadIdx.x;  // B*S*NH*64 threads
  int d = idx & 63;
  int h = (idx >> 6) & 31;
  int bs = idx >> 11;
  int b = bs >> 11, s = bs & 2047;
  float pos = (float)pos_ids[bs];
  float inv = exp2f(-(float)d * (13.287712379549449f / 64.0f));
  float fr = pos * inv, sn, cs;
  sincosf(fr, &sn, &cs);
  long bi = (long)bs * 4096 + h * 128 + d;
  long bo = ((long)(b * 32 + h) * 2048 + s) * 128 + d;
  float x1 = __bfloat162float(in[bi]);
  float x2 = __bfloat162float(in[bi + 64]);
  out[bo] = __float2bfloat16(x1 * cs - x2 * sn);
  out[bo + 64] = __float2bfloat16(x2 * cs + x1 * sn);
}

// -------- transpose v_lat (b,s,2048) -> tiled Vt: (b,g,kt) blocks of (256 x 64) ----
__global__ __launch_bounds__(256) void transpose_kernel(const bf16* __restrict__ v,
                                                        bf16* __restrict__ vt) {
  __shared__ bf16 tile[32][33];
  int b = blockIdx.z;
  int c0 = blockIdx.x * 32;  // column in 2048 (= g*256 + d)
  int r0 = blockIdx.y * 32;  // row (s)
  int tx = threadIdx.x & 31, ty = threadIdx.x >> 5;
#pragma unroll
  for (int p = 0; p < 4; ++p) {
    int r = ty + p * 8;
    tile[r][tx] = v[((long)b * 2048 + r0 + r) * 2048 + c0 + tx];
  }
  __syncthreads();
#pragma unroll
  for (int p = 0; p < 4; ++p) {
    int cidx = ty + p * 8;
    int cg = c0 + cidx;          // global column = g*256 + d
    int g = cg >> 8, d = cg & 255;
    int s = r0 + tx;
    vt[((long)((b * 8 + g) * 32 + (s >> 6))) * 16384 + d * 64 + (s & 63)] = tile[tx][cidx];
  }
}

// ---------------- flash attention v3: contiguous tiles, coalesced epilogue --------
// grid (S/128 reversed, NH, B), 512 threads; wave w owns q rows [q0+16w, +16)
// Q,K: (B,NH,S,128) head-major. Vt: tiled (b,g,kt,256x64). fused: (B,S,8192).
__global__ __launch_bounds__(512, 4) void attn_kernel(const bf16* __restrict__ Q,
                                                      const bf16* __restrict__ Kg,
                                                      const bf16* __restrict__ Vt,
                                                      bf16* __restrict__ fused) {
  __shared__ alignas(16) bf16 smem[32768];  // 64 KB
  bf16* Ks = smem;           // 64 x 128 (8192)
  bf16* Vs = smem + 8192;    // 256 x 64 (16384)
  bf16* Ps = smem + 24576;   // 8 waves x 16 x 64 (8192)
  const int t = threadIdx.x, w = t >> 6, l = t & 63;
  const int lane_r = l & 15, quad = l >> 4;
  const int qt = (int)gridDim.x - 1 - (int)blockIdx.x;  // long blocks dispatch first
  const int q0 = qt * 128, h = blockIdx.y, b = blockIdx.z;
  const int g = h >> 2, j = h & 3;
  const int qr0 = q0 + w * 16;
  const float scale = 0.08838834764831845f;  // 1/sqrt(128)

  // Q fragments (A-operand: m=lane&15, k=quad*8+jj), head-major contiguous rows
  const bf16* qbase = Q + ((long)(b * 32 + h) * 2048 + qr0 + lane_r) * 128 + quad * 8;
  bf16x8 qf[4];
#pragma unroll
  for (int kd = 0; kd < 4; ++kd) qf[kd] = *(const bf16x8*)(qbase + kd * 32);

  f32x4 acc[16] = {};
  float m_i[4], l_i[4];
#pragma unroll
  for (int r = 0; r < 4; ++r) { m_i[r] = -1e30f; l_i[r] = 0.f; }

  const bf16* Kbase = Kg + (long)(b * 32 + h) * 2048 * 128;
  const bf16* Vtg = Vt + (long)(b * 8 + g) * 32 * 16384;
  const int nk = (q0 >> 6) + 2;

  for (int kt = 0; kt < nk; ++kt) {
    const int k0 = kt * 64;
    // stage K tile 64x128 = contiguous 16KB; chunk r*16+c stored at slot c^(r&15)
#pragma unroll
    for (int p = 0; p < 2; ++p) {
      int s = t + p * 512;
      int r = s >> 4, c = (s & 15) ^ (r & 15);
      llds16(Kbase + (long)(k0 + r) * 128 + c * 8, &Ks[s * 8]);
    }
    // stage Vt tile 256x64 = contiguous 32KB; chunk r*8+c stored at slot c^(r&7)
    const bf16* Vbase = Vtg + (long)kt * 16384;
#pragma unroll
    for (int p = 0; p < 4; ++p) {
      int s = t + p * 512;
      int r = s >> 3, c = (s & 7) ^ (r & 7);
      llds16(Vbase + r * 64 + c * 8, &Vs[s * 8]);
    }
    __syncthreads();

    // QK^T: 16 rows x 64 cols per wave
    float sc[4][4];
#pragma unroll
    for (int ks = 0; ks < 4; ++ks) {
      f32x4 s = {};
#pragma unroll
      for (int kd = 0; kd < 4; ++kd) {
        int csw = (kd * 4 + quad) ^ lane_r;  // row&15 == lane_r
        bf16x8 kf = *(const bf16x8*)&Ks[(ks * 16 + lane_r) * 128 + csw * 8];
        s = MFMA16(qf[kd], kf, s);
      }
      const int kv = k0 + ks * 16 + lane_r;
#pragma unroll
      for (int r = 0; r < 4; ++r) {
        int qrow = qr0 + quad * 4 + r;
        sc[ks][r] = (kv <= qrow) ? s[r] * scale : -1e30f;
      }
    }
    // online softmax per row
#pragma unroll
    for (int r = 0; r < 4; ++r) {
      float mx = fmaxf(fmaxf(sc[0][r], sc[1][r]), fmaxf(sc[2][r], sc[3][r]));
#pragma unroll
      for (int o = 1; o < 16; o <<= 1) mx = fmaxf(mx, __shfl_xor(mx, o));
      float mnew = fmaxf(m_i[r], mx);
      float alpha = __expf(m_i[r] - mnew);
      float rs = 0.f;
#pragma unroll
      for (int ks = 0; ks < 4; ++ks) {
        float p = __expf(sc[ks][r] - mnew);
        sc[ks][r] = p;
        rs += p;
      }
#pragma unroll
      for (int o = 1; o < 16; o <<= 1) rs += __shfl_xor(rs, o);
      l_i[r] = l_i[r] * alpha + rs;
      m_i[r] = mnew;
#pragma unroll
      for (int nt = 0; nt < 16; ++nt) acc[nt][r] *= alpha;
    }
    // P: C-layout -> LDS (swizzled), wave-private
    bf16* Pw = Ps + w * 1024;
#pragma unroll
    for (int ks = 0; ks < 4; ++ks)
#pragma unroll
      for (int r = 0; r < 4; ++r) {
        int row = quad * 4 + r, col = ks * 16 + lane_r;
        int csw = ((col >> 3) ^ (row & 7));
        Pw[row * 64 + csw * 8 + (col & 7)] = __float2bfloat16(sc[ks][r]);
      }
    // PV
#pragma unroll
    for (int kq = 0; kq < 2; ++kq) {
      int cs2 = (kq * 4 + quad) ^ (lane_r & 7);
      bf16x8 pf = *(const bf16x8*)&Pw[lane_r * 64 + cs2 * 8];
#pragma unroll
      for (int nt = 0; nt < 16; ++nt) {
        bf16x8 vf = *(const bf16x8*)&Vs[(nt * 16 + lane_r) * 64 + cs2 * 8];
        acc[nt] = MFMA16(pf, vf, acc[nt]);
      }
    }
    __syncthreads();
  }
  // ---- epilogue: normalize, stage 16x256 per wave in LDS, coalesced 16B stores ----
  bf16* EP = smem + w * 4096;  // 16 rows x 256 cols (reuses tile memory)
#pragma unroll
  for (int r = 0; r < 4; ++r) {
    float inv = 1.0f / l_i[r];
#pragma unroll
    for (int nt = 0; nt < 16; ++nt)
      EP[(quad * 4 + r) * 256 + nt * 16 + lane_r] = __float2bfloat16(acc[nt][r] * inv);
  }
  __syncthreads();
  // attn row qrow of head (g,j) -> s = j*512 + qrow/4, slot fi = qrow&3
#pragma unroll
  for (int op = 0; op < 8; ++op) {
    int row = op * 2 + (l >> 5);
    int qrow = qr0 + row;
    int sOut = j * 512 + (qrow >> 2), fi = qrow & 3;
    bf16x8 vread = *(const bf16x8*)&EP[row * 256 + (l & 31) * 8];
    *(bf16x8*)(fused + ((long)(b * 2048 + sOut)) * 8192 + fi * 2048 + g * 256 +
               (l & 31) * 8) = vread;
  }
}

// ---------------- launch ----------------
extern "C" void kernel_launch(void* const* d_in, const int* in_sizes, int n_in,
                              void* d_out, int out_size, void* d_ws, size_t ws_size,
                              hipStream_t stream) {
  const float* hidden = (const float*)d_in[0];
  const int* pos_ids = (const int*)d_in[2];
  const float* Wq = (const float*)d_in[3];
  const float* WVT = (const float*)d_in[4];
  const float* U = (const float*)d_in[5];
  const float* Wv = (const float*)d_in[6];
  const float* Wo = (const float*)d_in[7];
  float* out = (float*)d_out;

  bf16* ws = (bf16*)d_ws;
  bf16* WB = ws;                    // 33554432 (reused for Wq/WVT/Wv/Wo)
  bf16* UB = WB + 33554432;         // 1048576
  bf16* hidB = UB + 1048576;        // 16777216  (later reused as Qh)
  bf16* Qb = hidB + 16777216;       // 16777216
  bf16* Kb = Qb + 16777216;         // 16777216
  bf16* klatB = Kb + 16777216;      // 8388608   (klatB+vlatB later reused as Kh)
  bf16* vlatB = klatB + 8388608;    // 8388608
  bf16* vtB = vlatB + 8388608;      // 8388608   (tiled Vt)
  bf16* fusedB = vtB + 8388608;     // 33554432
  bf16* Qh = hidB;
  bf16* Kh = klatB;

  cvt_f2b<<<16384, 256, 0, stream>>>(hidden, hidB, 16777216 / 4);
  cvt_f2b<<<16384, 256, 0, stream>>>(Wq, WB, 16777216 / 4);
  gemm_bt<bf16><<<dim3(32, 32, 1), 256, 0, stream>>>(hidB, WB, Qb, 4096, 4096, 4096,
                                                     4096, 4096, 4096, 0, 0, 0);
  cvt_f2b<<<8192, 256, 0, stream>>>(WVT, WB, 8388608 / 4);
  gemm_bt<bf16><<<dim3(16, 32, 1), 256, 0, stream>>>(hidB, WB, klatB, 4096, 2048, 4096,
                                                     4096, 4096, 2048, 0, 0, 0);
  cvt_f2b<<<8192, 256, 0, stream>>>(Wv, WB, 8388608 / 4);
  gemm_bt<bf16><<<dim3(16, 32, 1), 256, 0, stream>>>(hidB, WB, vlatB, 4096, 2048, 4096,
                                                     4096, 4096, 2048, 0, 0, 0);
  cvt_f2b<<<1024, 256, 0, stream>>>(U, UB, 1048576 / 4);
  gemm_bt<bf16><<<dim3(4, 32, 8), 256, 0, stream>>>(klatB, UB, Kb, 4096, 512, 256,
                                                    2048, 2048, 4096, 256, 256, 512);
  transpose_kernel<<<dim3(64, 64, 2), 256, 0, stream>>>(vlatB, vtB);  // before Kh reuse
  rope_perm<<<32768, 256, 0, stream>>>(Qb, Qh, pos_ids);
  rope_perm<<<32768, 256, 0, stream>>>(Kb, Kh, pos_ids);
  cvt_f2b<<<32768, 256, 0, stream>>>(Wo, WB, 33554432 / 4);
  attn_kernel<<<dim3(16, 32, 2), 512, 0, stream>>>(Qh, Kh, vtB, fusedB);
  gemm_bt<float><<<dim3(32, 32, 1), 256, 0, stream>>>(fusedB, WB, out, 4096, 4096, 8192,
                                                      8192, 8192, 4096, 0, 0, 0);
}